// Round 1
// 379.441 us; speedup vs baseline: 1.0068x; 1.0068x over previous
//
#include <hip/hip_runtime.h>

#define NPIX (1024 * 1024)
#define NBATCH 16
#define NBINS 8192
#define SUBPB 32      // sub-histogram blocks per batch
#define HTHREADS 512

typedef float vfloat4 __attribute__((ext_vector_type(4)));

// ---------------------------------------------------------------------------
// Kernel 1: per-block LDS histogram of luminance. Each block writes its
// PRIVATE 8192-bin histogram to global with plain coalesced stores — no
// global atomics (the old 64-way-contended 8.4M-atomic flush was the theory'd
// bottleneck). Reads ALL of img -> warms Infinity Cache for the apply pass.
// ---------------------------------------------------------------------------
__global__ __launch_bounds__(HTHREADS) void hist_kernel(
        const float* __restrict__ img,
        const float* __restrict__ rgb2yuv,
        unsigned int* __restrict__ ghist) {
    __shared__ unsigned int lh[NBINS];
    for (int i = threadIdx.x; i < NBINS; i += HTHREADS) lh[i] = 0;
    const float c0 = rgb2yuv[0];
    const float c1 = rgb2yuv[1];
    const float c2 = rgb2yuv[2];
    __syncthreads();

    const int b = blockIdx.x / SUBPB;
    const int s = blockIdx.x % SUBPB;
    const int pixPerBlock = NPIX / SUBPB;  // 32768
    const size_t base = (size_t)b * 3 * NPIX + (size_t)s * pixPerBlock;

    const float4* r4 = (const float4*)(img + base);
    const float4* g4 = (const float4*)(img + base + NPIX);
    const float4* b4 = (const float4*)(img + base + 2 * (size_t)NPIX);
    const int n4 = pixPerBlock / 4;  // 8192

    const float scale = (float)NBINS;
    for (int i = threadIdx.x; i < n4; i += HTHREADS) {
        float4 R = r4[i];
        float4 G = g4[i];
        float4 B = b4[i];
        float y0 = c0 * R.x + c1 * G.x + c2 * B.x;
        float y1 = c0 * R.y + c1 * G.y + c2 * B.y;
        float y2 = c0 * R.z + c1 * G.z + c2 * B.z;
        float y3 = c0 * R.w + c1 * G.w + c2 * B.w;
        int i0 = min(NBINS - 1, max(0, (int)(y0 * scale)));
        int i1 = min(NBINS - 1, max(0, (int)(y1 * scale)));
        int i2 = min(NBINS - 1, max(0, (int)(y2 * scale)));
        int i3 = min(NBINS - 1, max(0, (int)(y3 * scale)));
        atomicAdd(&lh[i0], 1u);
        atomicAdd(&lh[i1], 1u);
        atomicAdd(&lh[i2], 1u);
        atomicAdd(&lh[i3], 1u);
    }
    __syncthreads();

    // Non-atomic flush of the private histogram (fully overwrites its slot,
    // so no pre-zeroing of ghist is needed).
    uint4* dst = (uint4*)(ghist + (size_t)blockIdx.x * NBINS);
    const uint4* src = (const uint4*)lh;
    for (int i = threadIdx.x; i < NBINS / 4; i += HTHREADS) dst[i] = src[i];
}

// ---------------------------------------------------------------------------
// Kernel 2: one block per batch. Reduce the 32 sub-histograms (coalesced
// uint4 loads: lane-consecutive 32B chunks -> contiguous 2KB/wave), then
// scan, locate the 4 order statistics (10485,10486 / 1038089,1038090),
// interpolate within bin, write (blkpt, mult) per batch.
// ---------------------------------------------------------------------------
__global__ __launch_bounds__(1024) void scan_kernel(
        const unsigned int* __restrict__ ghist,
        float* __restrict__ stats) {
    __shared__ unsigned int hist[NBINS];
    __shared__ unsigned int segsum[1024];
    __shared__ float vals[4];

    const int b = blockIdx.x;
    const int t = threadIdx.x;

    // Reduce SUBPB sub-histograms; thread t owns contiguous bins [8t, 8t+8).
    unsigned int a[8] = {0u, 0u, 0u, 0u, 0u, 0u, 0u, 0u};
    for (int s = 0; s < SUBPB; ++s) {
        const uint4* p =
            (const uint4*)(ghist + ((size_t)b * SUBPB + s) * NBINS + t * 8);
        uint4 v0 = p[0];
        uint4 v1 = p[1];
        a[0] += v0.x; a[1] += v0.y; a[2] += v0.z; a[3] += v0.w;
        a[4] += v1.x; a[5] += v1.y; a[6] += v1.z; a[7] += v1.w;
    }
    unsigned int ss = 0;
#pragma unroll
    for (int j = 0; j < 8; ++j) {
        hist[t * 8 + j] = a[j];
        ss += a[j];
    }
    segsum[t] = ss;
    __syncthreads();

    // Hillis-Steele inclusive scan over 1024 segment sums
    for (int off = 1; off < 1024; off <<= 1) {
        unsigned int v = segsum[t];
        unsigned int add = (t >= off) ? segsum[t - off] : 0u;
        __syncthreads();
        segsum[t] = v + add;
        __syncthreads();
    }

    const unsigned int cumincl = segsum[t];
    const unsigned int cumbefore = (t > 0) ? segsum[t - 1] : 0u;

    const unsigned int ranks[4] = {10485u, 10486u, 1038089u, 1038090u};
    const int BPT = NBINS / 1024;  // 8
#pragma unroll
    for (int q = 0; q < 4; ++q) {
        unsigned int r = ranks[q];
        if (r >= cumbefore && r < cumincl) {
            unsigned int running = cumbefore;
#pragma unroll
            for (int j = 0; j < BPT; ++j) {
                unsigned int c = hist[t * BPT + j];
                if (r < running + c) {
                    float v = ((float)(t * BPT + j) +
                               ((float)(r - running) + 0.5f) / (float)c) *
                              (1.0f / (float)NBINS);
                    vals[q] = v;
                    break;
                }
                running += c;
            }
        }
    }
    __syncthreads();

    if (t == 0) {
        float blk = 0.25f * vals[0] + 0.75f * vals[1];
        float wht = 0.75f * vals[2] + 0.25f * vals[3];
        float mult = fminf(1.0f / (wht - blk), 1.5f);
        stats[b * 2 + 0] = blk;
        stats[b * 2 + 1] = mult;
    }
}

// ---------------------------------------------------------------------------
// Kernel 3: out = clip((img - blk[b]) * mult[b], 0, 1).
// Reads img (L3-resident after hist); writes out with NON-TEMPORAL stores
// so the write stream does not evict img from the Infinity Cache.
// ---------------------------------------------------------------------------
__global__ __launch_bounds__(256) void apply_kernel(
        const float* __restrict__ img,
        const float* __restrict__ stats,
        float* __restrict__ out) {
    const int blocksPerBatch = (3 * NPIX / 4) / 1024;  // 768
    const int b = blockIdx.x / blocksPerBatch;
    const int c = blockIdx.x % blocksPerBatch;
    const float blk = stats[b * 2 + 0];
    const float mult = stats[b * 2 + 1];

    const vfloat4* in4 =
        (const vfloat4*)(img + (size_t)b * 3 * NPIX) + (size_t)c * 1024;
    vfloat4* out4 = (vfloat4*)(out + (size_t)b * 3 * NPIX) + (size_t)c * 1024;

#pragma unroll
    for (int i = 0; i < 4; ++i) {
        int idx = i * 256 + threadIdx.x;
        vfloat4 v = in4[idx];
        v.x = fminf(fmaxf((v.x - blk) * mult, 0.0f), 1.0f);
        v.y = fminf(fmaxf((v.y - blk) * mult, 0.0f), 1.0f);
        v.z = fminf(fmaxf((v.z - blk) * mult, 0.0f), 1.0f);
        v.w = fminf(fmaxf((v.w - blk) * mult, 0.0f), 1.0f);
        __builtin_nontemporal_store(v, out4 + idx);
    }
}

extern "C" void kernel_launch(void* const* d_in, const int* in_sizes, int n_in,
                              void* d_out, int out_size, void* d_ws, size_t ws_size,
                              hipStream_t stream) {
    const float* img = (const float*)d_in[0];
    const float* rgb2yuv = (const float*)d_in[1];
    float* out = (float*)d_out;

    // Workspace layout: [0,128): stats (16 * {blk, mult});
    // [256, 256 + 512*8192*4): per-block sub-histograms (16 MB).
    float* stats = (float*)d_ws;
    unsigned int* ghist = (unsigned int*)((char*)d_ws + 256);

    hist_kernel<<<NBATCH * SUBPB, HTHREADS, 0, stream>>>(img, rgb2yuv, ghist);
    scan_kernel<<<NBATCH, 1024, 0, stream>>>(ghist, stats);

    const int applyBlocks = NBATCH * ((3 * NPIX / 4) / 1024);  // 12288
    apply_kernel<<<applyBlocks, 256, 0, stream>>>(img, stats, out);
}